// Round 4
// baseline (332.063 us; speedup 1.0000x reference)
//
#include <hip/hip_runtime.h>

// iRPE contextual/transposed PRODUCT, round-9: MEASUREMENT PROBE.
//
// r5-r8 post-mortem: four structural rewrites (store decomposition, fused
// vs split, bucket table vs arithmetic, nt vs plain stores) all land at
// kernel ~135-155 us (~2 TB/s effective write BW) while fillBufferAligned
// sustains 6.4 TB/s write-only on the same chip. Our kernel has never
// appeared in rocprof top-5 (every dispatch < ~165 us) so we have ZERO
// direct counters for it. This round: fused kernel stores its tile THREE
// times (same addresses, barrier+clobber between passes, plain stores,
// bitwise-identical output) to push one dispatch above the ~170 us fills
// and expose WRITE_SIZE / FETCH_SIZE / VALUBusy / Occupancy for OUR kernel.
//
// Pre-committed readout:
//  - top-5 @ ~390us, WRITE~790MB, hbm~2TB/s           -> write path capped
//  -   ... with FETCH_SIZE ~256MB                      -> read-for-ownership
//  - top-5 @ ~180-220us, WRITE~790MB, hbm>=4TB/s       -> stores fast; orig
//    kernel is stall-bound; read VALUBusy/Occupancy     (attack stalls next)
//  - absent & dur ~310-330                              -> stores merged in
//    L2; writeback drain is the cap                     (bypass L2 next)

constexpr int cL  = 1024;
constexpr int cD  = 64;
constexpr int cK  = 49;
constexpr int cIT = 8;    // i rows per block

typedef float vf4 __attribute__((ext_vector_type(4)));

// piecewise_index(d) + BETA_INT for this config (verified absmax 0.0)
__device__ __forceinline__ int bucket_c(int d) {
    int a = d < 0 ? -d : d;
    int m = a < 4 ? a : 4;     // min(|d|,4)
    m -= (m >= 3) ? 1 : 0;     // q(|d|) = {0,1,2,2,3,3,...}
    int p = d < 0 ? -m : m;
    return p + 3;
}

__global__ __launch_bounds__(256) void irpe_fused_probe(
    const float* __restrict__ x,   // (bh, i, d)
    const float* __restrict__ W,   // (h, d, k)
    float*       __restrict__ out) // (bh, i, j)
{
    __shared__ vf4   xs4[cIT][cD / 4];
    __shared__ float lts[cIT * cK];

    const int gid = blockIdx.x;
    const int bh  = gid & 63;
    const int it  = gid >> 6;
    const int i0  = it * cIT;
    const int h   = bh & 7;
    const int tid = threadIdx.x;

    // ---- Phase A: stage 8 x rows (2 KB) ----
    if (tid < cIT * (cD / 4)) {
        const int li = tid >> 4;
        const int dq = tid & 15;
        xs4[li][dq] =
            ((const vf4*)x)[((size_t)bh * cL + (i0 + li)) * (cD / 4) + dq];
    }
    __syncthreads();

    // ---- Phase B: lt GEMV (same fmaf chain as r5-r8 -> identical bits) ----
    for (int p = tid; p < cIT * cK; p += 256) {
        const int li = p / cK;
        const int k  = p - li * cK;
        const float* wp = W + (size_t)h * cD * cK + k;
        const float* xr = (const float*)&xs4[li][0];
        float acc = 0.0f;
        #pragma unroll
        for (int d = 0; d < cD; ++d) acc = fmaf(xr[d], wp[(size_t)d * cK], acc);
        lts[p] = acc;
    }
    __syncthreads();

    // ---- Phase C: arithmetic buckets ----
    const int j0   = tid * 4;
    const int xj   = j0 & 31;
    const int yj   = j0 >> 5;
    const int yi   = i0 >> 5;
    const int xi0  = i0 & 31;
    const int rbase = 7 * bucket_c(yi - yj);
    const int base  = xi0 - xj;
    int cv[11];
    #pragma unroll
    for (int t = 0; t < 11; ++t) cv[t] = rbase + bucket_c(base + t - 3);

    // ---- PROBE: store the tile 3x (same addresses, plain stores) ----
    vf4* obase = (vf4*)(out + ((size_t)bh * cL + i0) * cL);
    for (int pass = 0; pass < 3; ++pass) {
        #pragma unroll
        for (int il = 0; il < cIT; ++il) {
            const float* lrow = lts + il * cK;
            vf4 o;
            o.x = lrow[cv[il + 3]];
            o.y = lrow[cv[il + 2]];
            o.z = lrow[cv[il + 1]];
            o.w = lrow[cv[il + 0]];
            obase[(size_t)il * (cL / 4) + tid] = o;
        }
        // keep the redundant passes: no DSE across barrier + clobber
        __syncthreads();
        asm volatile("" ::: "memory");
    }
}

extern "C" void kernel_launch(void* const* d_in, const int* in_sizes, int n_in,
                              void* d_out, int out_size, void* d_ws, size_t ws_size,
                              hipStream_t stream) {
    const float* x   = (const float*)d_in[0];   // (8,8,1024,64) fp32
    const float* W   = (const float*)d_in[1];   // (8,64,49) fp32
    float*       out = (float*)d_out;           // (8,8,1024,1024) fp32

    irpe_fused_probe<<<64 * (cL / cIT), 256, 0, stream>>>(x, W, out);
}